// Round 10
// baseline (220.290 us; speedup 1.0000x reference)
//
#include <hip/hip_runtime.h>

#define NB_BITS     11
#define N_BUCKETS   (1 << NB_BITS)            // 2048 buckets (top 11 key bits)
#define LOCAL_BITS  18                        // low 18 bits -> 8192-word bitmap
#define LOCAL_WORDS 8192                      // 32 KB
#define LKMASK      ((1u << LOCAL_BITS) - 1u)
#define KEYMASK     0x1FFFFFFFu
#define NXCD        8
#define WCAP        512                       // per-(bucket,xcd) window: mean 244, +17 sigma
#define WSHIFT      9                         // log2(WCAP)
#define FE_CAP      2560                      // unique/bucket: mean 1946, +13 sigma
#define PPT         8                         // points per thread per tile
#define TILE        (1024 * PPT)              // 8192 points per block

#define ST_AGG      (1u << 30)
#define ST_PRE      (2u << 30)
#define VALMASK     0x3FFFFFFFu

__device__ __forceinline__ unsigned make_key(int4 c) {
    return ((((unsigned)c.x << 7) | (unsigned)(c.y >> 1)) << 7 | (unsigned)(c.z >> 1)) << 7
         | (unsigned)(c.w >> 1);
}

// exclusive block scan over NW waves; 2 internal barriers
template<int NW>
__device__ inline void block_scan(unsigned v, unsigned* wsum, unsigned& excl, unsigned& total) {
    int t = threadIdx.x, ln = t & 63, wv = t >> 6;
    unsigned incl = v;
    #pragma unroll
    for (int off = 1; off < 64; off <<= 1) {
        unsigned y = __shfl_up(incl, off, 64);
        if (ln >= off) incl += y;
    }
    if (ln == 63) wsum[wv] = incl;
    __syncthreads();
    if (wv == 0) {
        unsigned s = (ln < NW) ? wsum[ln] : 0u;
        #pragma unroll
        for (int off = 1; off < NW; off <<= 1) {
            unsigned y = __shfl_up(s, off, 64);
            if (ln >= off) s += y;
        }
        if (ln < NW) wsum[ln] = s;
    }
    __syncthreads();
    excl = (wv ? wsum[wv - 1] : 0u) + incl - v;
    total = wsum[NW - 1];
}

// 8-lane window prefix -> gb[0..8]; gcur layout is [xcd][bucket]
__device__ __forceinline__ void gb_setup(const unsigned* gcur, int b, unsigned* gb) {
    int t = threadIdx.x;
    unsigned gv = 0;
    if (t < 8) gv = min(gcur[(unsigned)t * N_BUCKETS + (unsigned)b], (unsigned)WCAP);
    if (t < 64) {
        unsigned incl = gv;
        #pragma unroll
        for (int off = 1; off < 8; off <<= 1) {
            unsigned y = __shfl_up(incl, off, 64);
            if (t >= off) incl += y;
        }
        if (t < 8) gb[t + 1] = incl;
        if (t == 0) gb[0] = 0u;
    }
}

// ---- pass 1: LDS hist + per-block window reserve + scatter (R8-verbatim) ----
__global__ void __launch_bounds__(1024, 8)
build_pass(const int4* __restrict__ coords,
           unsigned* __restrict__ gcur,     // [NXCD][N_BUCKETS] cursors
           unsigned* __restrict__ pairs,    // [N_BUCKETS][NXCD][WCAP]
           int n) {
    __shared__ unsigned h[N_BUCKETS];        // 8 KB: counts -> block's window bases
    int t = threadIdx.x, blk = blockIdx.x;
    unsigned xcd = (unsigned)blk & 7u;
    int base = blk * TILE;
    unsigned skey[PPT], lrank[PPT];
    h[t] = 0u; h[t + 1024] = 0u;
    #pragma unroll
    for (int m = 0; m < PPT; ++m) {
        int i = base + t + m * 1024;
        if (i < n) {
            int4 c = coords[i];
            unsigned key = make_key(c);
            unsigned pos = (unsigned)((c.y & 1) | ((c.z & 1) << 1) | ((c.w & 1) << 2));
            skey[m] = (pos << 29) | key;
        }
    }
    __syncthreads();
    #pragma unroll
    for (int m = 0; m < PPT; ++m) {
        int i = base + t + m * 1024;
        if (i < n)
            lrank[m] = atomicAdd(&h[(skey[m] & KEYMASK) >> LOCAL_BITS], 1u);
    }
    __syncthreads();
    #pragma unroll
    for (int q = 0; q < 2; ++q) {
        int j = t + q * 1024;
        unsigned c = h[j];
        if (c) h[j] = atomicAdd(&gcur[xcd * N_BUCKETS + (unsigned)j], c);  // count -> base
    }
    __syncthreads();
    #pragma unroll
    for (int m = 0; m < PPT; ++m) {
        int i = base + t + m * 1024;
        if (i < n) {
            unsigned b = (skey[m] & KEYMASK) >> LOCAL_BITS;
            unsigned o = h[b] + lrank[m];
            if (o < WCAP)                                     // +17 sigma guard
                pairs[(((b << 3) | xcd) << WSHIFT) + o] = skey[m];
        }
    }
}

// ---- pass 2: fused count+emit; lookback hidden under the feats phase ----
__global__ void __launch_bounds__(1024, 8)
emit_pass(const unsigned* __restrict__ pairs,
          const unsigned* __restrict__ gcur,
          unsigned* __restrict__ pub,           // [N_BUCKETS] status|value
          const float* __restrict__ kern,
          float4* __restrict__ out_coords,
          float* __restrict__ out_feats, int n) {
    __shared__ unsigned       bm[LOCAL_WORDS];    // 32 KB
    __shared__ unsigned short pfx[LOCAL_WORDS];   // 16 KB
    __shared__ float          fe[FE_CAP];         // 10 KB
    __shared__ unsigned wsum[16];
    __shared__ unsigned gb[NXCD + 1];
    __shared__ unsigned ubS;
    __shared__ float    kl[8];
    int t = threadIdx.x, b = blockIdx.x;
    if (t < 8) kl[t] = (float)(1 << t) * kern[t];
    gb_setup(gcur, b, gb);
    ((uint4*)bm)[t] = make_uint4(0u, 0u, 0u, 0u);
    ((uint4*)bm)[t + 1024] = make_uint4(0u, 0u, 0u, 0u);
    for (int i = t; i < FE_CAP; i += 1024) fe[i] = 0.f;
    __syncthreads();
    unsigned tot = gb[NXCD];
    // pairs read ONCE into regs + bitmap build; pk[4] covers the full 8*WCAP=4096 bound
    unsigned pk[4];
    #pragma unroll
    for (int k = 0; k < 4; ++k) {
        unsigned p = (unsigned)t + (unsigned)k * 1024u;
        if (p < tot) {
            unsigned g = 0;
            #pragma unroll
            for (int j = 1; j < NXCD; ++j) g += (p >= gb[j]) ? 1u : 0u;
            unsigned v = pairs[((((unsigned)b << 3) | g) << WSHIFT) + (p - gb[g])];
            pk[k] = v;
            unsigned lk = v & LKMASK;
            atomicOr(&bm[lk >> 5], 1u << (lk & 31u));
        }
    }
    __syncthreads();
    // ordered word prefix: thread t owns words [8t, 8t+8)
    uint4 q0 = ((uint4*)bm)[2 * t], q1 = ((uint4*)bm)[2 * t + 1];
    unsigned pc[8] = { (unsigned)__popc(q0.x), (unsigned)__popc(q0.y),
                       (unsigned)__popc(q0.z), (unsigned)__popc(q0.w),
                       (unsigned)__popc(q1.x), (unsigned)__popc(q1.y),
                       (unsigned)__popc(q1.z), (unsigned)__popc(q1.w) };
    unsigned psum = 0;
    #pragma unroll
    for (int m = 0; m < 8; ++m) psum += pc[m];
    unsigned excl, cnt;
    block_scan<16>(psum, wsum, excl, cnt);
    if (t == 0)   // publish aggregate ASAP for successors' lookback
        __hip_atomic_store(&pub[b], ST_AGG | cnt, __ATOMIC_RELAXED, __HIP_MEMORY_SCOPE_AGENT);
    // packed pfx write: 8 ushorts -> one uint4, 16 B/lane contiguous
    {
        unsigned run = excl, pw[4];
        #pragma unroll
        for (int m = 0; m < 4; ++m) {
            unsigned lo = run & 0xFFFFu; run += pc[2 * m];
            unsigned hi = run & 0xFFFFu; run += pc[2 * m + 1];
            pw[m] = lo | (hi << 16);
        }
        ((uint4*)pfx)[t] = make_uint4(pw[0], pw[1], pw[2], pw[3]);
    }
    __syncthreads();
    // feats (waves 1..15) overlapped with wave-0 lookback; wave 0 feats after
    if (t >= 64) {
        #pragma unroll
        for (int k = 0; k < 4; ++k) {
            unsigned p = (unsigned)t + (unsigned)k * 1024u;
            if (p < tot) {
                unsigned v = pk[k];
                unsigned lk = v & LKMASK;
                unsigned wd = lk >> 5;
                unsigned lr = (unsigned)pfx[wd] + __popc(bm[wd] & ((1u << (lk & 31u)) - 1u));
                atomicAdd(&fe[lr], kl[v >> 29]);
            }
        }
    } else {
        // wave 0: decoupled lookback, 64 predecessors per step
        unsigned sum = 0;
        if (b > 0) {
            int j = b - 1;
            while (true) {
                int idx = j - 63 + t;
                unsigned v = (idx >= 0)
                    ? __hip_atomic_load(&pub[idx], __ATOMIC_RELAXED, __HIP_MEMORY_SCOPE_AGENT)
                    : (ST_PRE | 0u);
                unsigned st = v >> 30;
                unsigned long long vm = __ballot(st != 0u);
                if (vm != ~0ull) continue;                     // spin: window not ready
                unsigned long long pm = __ballot(st == 2u);
                unsigned val = v & VALMASK;
                if (pm) {
                    int lp = 63 - __clzll(pm);                 // highest PREFIX lane
                    unsigned red = (t >= lp) ? val : 0u;
                    #pragma unroll
                    for (int off = 1; off < 64; off <<= 1) red += __shfl_xor(red, off, 64);
                    sum += red;
                    break;
                }
                unsigned red = val;                            // all AGG: consume window
                #pragma unroll
                for (int off = 1; off < 64; off <<= 1) red += __shfl_xor(red, off, 64);
                sum += red;
                j -= 64;
            }
        }
        if (t == 0) {
            __hip_atomic_store(&pub[b], ST_PRE | (sum + cnt),
                               __ATOMIC_RELAXED, __HIP_MEMORY_SCOPE_AGENT);
            ubS = sum;
        }
        // wave 0's own feats contributions (pk cached in its regs)
        #pragma unroll
        for (int k = 0; k < 4; ++k) {
            unsigned p = (unsigned)t + (unsigned)k * 1024u;
            if (p < tot) {
                unsigned v = pk[k];
                unsigned lk = v & LKMASK;
                unsigned wd = lk >> 5;
                unsigned lr = (unsigned)pfx[wd] + __popc(bm[wd] & ((1u << (lk & 31u)) - 1u));
                atomicAdd(&fe[lr], kl[v >> 29]);
            }
        }
    }
    __syncthreads();
    unsigned ub = ubS;
    // coords: bitmap walk -> sequential sorted float4 stores
    unsigned wq[8] = { q0.x, q0.y, q0.z, q0.w, q1.x, q1.y, q1.z, q1.w };
    unsigned rr = ub + excl;
    #pragma unroll
    for (int m = 0; m < 8; ++m) {
        unsigned w = wq[m];
        unsigned hi = ((unsigned)b << LOCAL_BITS) | ((unsigned)(8 * t + m) << 5);
        while (w) {
            unsigned bit = (unsigned)__ffs(w) - 1u;
            w &= w - 1u;
            unsigned key = hi | bit;
            out_coords[rr++] = make_float4((float)(key >> 21),
                                           (float)((key >> 14) & 127u),
                                           (float)((key >> 7) & 127u),
                                           (float)(key & 127u));
        }
    }
    __syncthreads();
    for (unsigned i = (unsigned)t; i < cnt; i += 1024u)
        out_feats[ub + i] = fe[i];
    // tail fill by the LAST bucket's block: it alone knows T = ub + cnt.
    if (b == N_BUCKETS - 1) {
        unsigned T = ub + cnt;
        for (unsigned r = T + (unsigned)t; r < (unsigned)n; r += 1024u) {
            out_coords[r] = make_float4(-1.f, -1.f, -1.f, -1.f);
            out_feats[r] = 0.f;
        }
    }
}

extern "C" void kernel_launch(void* const* d_in, const int* in_sizes, int n_in,
                              void* d_out, int out_size, void* d_ws, size_t ws_size,
                              hipStream_t stream) {
    const int4* coords = (const int4*)d_in[0];
    const float* kern  = (const float*)d_in[1];
    int N = in_sizes[0] / 4;

    float* out = (float*)d_out;                   // [4N floats coords][N floats feats]
    float4* out_coords = (float4*)out;
    float* out_feats = out + (size_t)4 * N;

    unsigned* gcur  = (unsigned*)d_ws;                           // 64 KB cursors [xcd][bucket]
    unsigned* pub   = gcur + (size_t)N_BUCKETS * NXCD;           // 8 KB lookback states
    unsigned* pairs = pub + (size_t)N_BUCKETS;                   // 32 MB windows

    // zero gcur + pub in one shot (contiguous)
    hipMemsetAsync(gcur, 0, (size_t)(N_BUCKETS * NXCD + N_BUCKETS) * sizeof(unsigned), stream);

    int ntiles = (N + TILE - 1) / TILE;           // 489 for N=4M
    build_pass<<<ntiles, 1024, 0, stream>>>(coords, gcur, pairs, N);
    emit_pass<<<N_BUCKETS, 1024, 0, stream>>>(pairs, gcur, pub, kern,
                                              out_coords, out_feats, N);
}

// Round 11
// 194.231 us; speedup vs baseline: 1.1342x; 1.1342x over previous
//
#include <hip/hip_runtime.h>

#define NB_BITS     11
#define N_BUCKETS   (1 << NB_BITS)            // 2048 buckets (top 11 key bits)
#define LOCAL_BITS  18                        // low 18 bits -> 8192-word bitmap
#define LOCAL_WORDS 8192                      // 32 KB
#define LKMASK      ((1u << LOCAL_BITS) - 1u)
#define KEYMASK     0x1FFFFFFFu
#define NXCD        8
#define WCAP        512                       // per-(bucket,xcd) window: mean 244, +17 sigma
#define WSHIFT      9                         // log2(WCAP)
#define FE_CAP      2560                      // unique/bucket: mean 1946, +13 sigma
#define PPT         8                         // points per thread per tile
#define TILE        (1024 * PPT)              // 8192 points per block

__device__ __forceinline__ unsigned make_key(int4 c) {
    return ((((unsigned)c.x << 7) | (unsigned)(c.y >> 1)) << 7 | (unsigned)(c.z >> 1)) << 7
         | (unsigned)(c.w >> 1);
}

// exclusive block scan over NW waves; 2 internal barriers
template<int NW>
__device__ inline void block_scan(unsigned v, unsigned* wsum, unsigned& excl, unsigned& total) {
    int t = threadIdx.x, ln = t & 63, wv = t >> 6;
    unsigned incl = v;
    #pragma unroll
    for (int off = 1; off < 64; off <<= 1) {
        unsigned y = __shfl_up(incl, off, 64);
        if (ln >= off) incl += y;
    }
    if (ln == 63) wsum[wv] = incl;
    __syncthreads();
    if (wv == 0) {
        unsigned s = (ln < NW) ? wsum[ln] : 0u;
        #pragma unroll
        for (int off = 1; off < NW; off <<= 1) {
            unsigned y = __shfl_up(s, off, 64);
            if (ln >= off) s += y;
        }
        if (ln < NW) wsum[ln] = s;
    }
    __syncthreads();
    excl = (wv ? wsum[wv - 1] : 0u) + incl - v;
    total = wsum[NW - 1];
}

// 8-lane window prefix -> gb[0..8]; gcur layout is [xcd][bucket]
__device__ __forceinline__ void gb_setup(const unsigned* gcur, int b, unsigned* gb) {
    int t = threadIdx.x;
    unsigned gv = 0;
    if (t < 8) gv = min(gcur[(unsigned)t * N_BUCKETS + (unsigned)b], (unsigned)WCAP);
    if (t < 64) {
        unsigned incl = gv;
        #pragma unroll
        for (int off = 1; off < 8; off <<= 1) {
            unsigned y = __shfl_up(incl, off, 64);
            if (t >= off) incl += y;
        }
        if (t < 8) gb[t + 1] = incl;
        if (t == 0) gb[0] = 0u;
    }
}

// ---- pass 1: LDS hist + per-block window reserve + scatter (R8-verbatim) ----
__global__ void __launch_bounds__(1024, 8)
build_pass(const int4* __restrict__ coords,
           unsigned* __restrict__ gcur,     // [NXCD][N_BUCKETS] cursors
           unsigned* __restrict__ pairs,    // [N_BUCKETS][NXCD][WCAP]
           int n) {
    __shared__ unsigned h[N_BUCKETS];        // 8 KB: counts -> block's window bases
    int t = threadIdx.x, blk = blockIdx.x;
    unsigned xcd = (unsigned)blk & 7u;
    int base = blk * TILE;
    unsigned skey[PPT], lrank[PPT];
    h[t] = 0u; h[t + 1024] = 0u;
    #pragma unroll
    for (int m = 0; m < PPT; ++m) {
        int i = base + t + m * 1024;
        if (i < n) {
            int4 c = coords[i];
            unsigned key = make_key(c);
            unsigned pos = (unsigned)((c.y & 1) | ((c.z & 1) << 1) | ((c.w & 1) << 2));
            skey[m] = (pos << 29) | key;
        }
    }
    __syncthreads();
    #pragma unroll
    for (int m = 0; m < PPT; ++m) {
        int i = base + t + m * 1024;
        if (i < n)
            lrank[m] = atomicAdd(&h[(skey[m] & KEYMASK) >> LOCAL_BITS], 1u);
    }
    __syncthreads();
    #pragma unroll
    for (int q = 0; q < 2; ++q) {
        int j = t + q * 1024;
        unsigned c = h[j];
        if (c) h[j] = atomicAdd(&gcur[xcd * N_BUCKETS + (unsigned)j], c);  // count -> base
    }
    __syncthreads();
    #pragma unroll
    for (int m = 0; m < PPT; ++m) {
        int i = base + t + m * 1024;
        if (i < n) {
            unsigned b = (skey[m] & KEYMASK) >> LOCAL_BITS;
            unsigned o = h[b] + lrank[m];
            if (o < WCAP)                                     // +17 sigma guard
                pairs[(((b << 3) | xcd) << WSHIFT) + o] = skey[m];
        }
    }
}

// ---- pass 2: unique count per bucket (R8-verbatim; 4 blocks/CU) ----
__global__ void __launch_bounds__(512, 8)
count_pass(const unsigned* __restrict__ pairs,
           const unsigned* __restrict__ gcur,
           unsigned* __restrict__ ucount) {
    __shared__ unsigned bm[LOCAL_WORDS];      // 32 KB
    __shared__ unsigned wsum[8];
    __shared__ unsigned gb[NXCD + 1];
    int t = threadIdx.x, b = blockIdx.x;
    gb_setup(gcur, b, gb);
    #pragma unroll
    for (int m = 0; m < 4; ++m)
        ((uint4*)bm)[t + 512 * m] = make_uint4(0u, 0u, 0u, 0u);
    __syncthreads();
    unsigned tot = gb[NXCD];
    for (unsigned p = (unsigned)t; p < tot; p += 512u) {
        unsigned g = 0;
        #pragma unroll
        for (int j = 1; j < NXCD; ++j) g += (p >= gb[j]) ? 1u : 0u;
        unsigned lk = pairs[((((unsigned)b << 3) | g) << WSHIFT) + (p - gb[g])] & LKMASK;
        atomicOr(&bm[lk >> 5], 1u << (lk & 31u));
    }
    __syncthreads();
    unsigned v = 0;
    #pragma unroll
    for (int m = 0; m < 16; ++m) v += __popc(bm[t + 512 * m]);   // stride-1 lanes: free
    int ln = t & 63;
    #pragma unroll
    for (int off = 1; off < 64; off <<= 1) v += __shfl_xor(v, off, 64);
    if (ln == 0) wsum[t >> 6] = v;
    __syncthreads();
    if (t == 0) {
        unsigned c = 0;
        #pragma unroll
        for (int m = 0; m < 8; ++m) c += wsum[m];
        ucount[b] = c;
    }
}

// ---- pass 3: emit; ubase scan OVERLAPPED with pairs load (R0 pattern, ----
// placed correctly this time: wave 0 scans WHILE waves 1-15 load+atomicOr).
__global__ void __launch_bounds__(1024, 8)
emit_pass(const unsigned* __restrict__ pairs,
          const unsigned* __restrict__ gcur,
          const unsigned* __restrict__ ucount,
          const float* __restrict__ kern,
          float4* __restrict__ out_coords,
          float* __restrict__ out_feats, int n) {
    __shared__ unsigned       bm[LOCAL_WORDS];    // 32 KB
    __shared__ unsigned short pfx[LOCAL_WORDS];   // 16 KB
    __shared__ float          fe[FE_CAP];         // 10 KB
    __shared__ unsigned wsum[16];
    __shared__ unsigned gb[NXCD + 1];
    __shared__ unsigned ubS, totS;
    __shared__ float    kl[8];
    int t = threadIdx.x, b = blockIdx.x;
    if (t < 8) kl[t] = (float)(1 << t) * kern[t];
    gb_setup(gcur, b, gb);
    ((uint4*)bm)[t] = make_uint4(0u, 0u, 0u, 0u);
    ((uint4*)bm)[t + 1024] = make_uint4(0u, 0u, 0u, 0u);
    for (int i = t; i < FE_CAP; i += 1024) fe[i] = 0.f;
    __syncthreads();
    unsigned tot = gb[NXCD];
    unsigned pk[5];                                // waves 1..15, stride 960: covers 4096
    if (t >= 64) {
        // waves 1..15: pairs read ONCE into regs + bitmap build
        #pragma unroll
        for (int k = 0; k < 5; ++k) {
            unsigned p = (unsigned)(t - 64) + (unsigned)k * 960u;
            if (p < tot) {
                unsigned g = 0;
                #pragma unroll
                for (int j = 1; j < NXCD; ++j) g += (p >= gb[j]) ? 1u : 0u;
                unsigned v = pairs[((((unsigned)b << 3) | g) << WSHIFT) + (p - gb[g])];
                pk[k] = v;
                unsigned lk = v & LKMASK;
                atomicOr(&bm[lk >> 5], 1u << (lk & 31u));
            }
        }
    } else {
        // wave 0 (concurrent): exclusive prefix of ucount up to b + grand total
        int ln = t;
        unsigned sum = 0;
        const uint4* uc4 = (const uint4*)ucount;
        #pragma unroll
        for (int q = 0; q < 8; ++q) {
            uint4 u = uc4[ln * 8 + q];
            sum += u.x + u.y + u.z + u.w;
        }
        unsigned incl = sum;
        #pragma unroll
        for (int off = 1; off < 64; off <<= 1) {
            unsigned y = __shfl_up(incl, off, 64);
            if (ln >= off) incl += y;
        }
        if (ln == 63) totS = incl;
        unsigned exclv = incl - sum;
        if (ln == (b >> 5)) {
            unsigned r = exclv;
            int lim = b & 31;
            for (int m = 0; m < lim; ++m) r += ucount[(b & ~31) + m];
            ubS = r;
        }
    }
    __syncthreads();
    // ordered word prefix: thread t owns words [8t, 8t+8)
    uint4 q0 = ((uint4*)bm)[2 * t], q1 = ((uint4*)bm)[2 * t + 1];
    unsigned pc[8] = { (unsigned)__popc(q0.x), (unsigned)__popc(q0.y),
                       (unsigned)__popc(q0.z), (unsigned)__popc(q0.w),
                       (unsigned)__popc(q1.x), (unsigned)__popc(q1.y),
                       (unsigned)__popc(q1.z), (unsigned)__popc(q1.w) };
    unsigned psum = 0;
    #pragma unroll
    for (int m = 0; m < 8; ++m) psum += pc[m];
    unsigned excl, cnt;
    block_scan<16>(psum, wsum, excl, cnt);
    // packed pfx write: 8 ushorts -> one uint4, 16 B/lane contiguous
    {
        unsigned run = excl, pw[4];
        #pragma unroll
        for (int m = 0; m < 4; ++m) {
            unsigned lo = run & 0xFFFFu; run += pc[2 * m];
            unsigned hi = run & 0xFFFFu; run += pc[2 * m + 1];
            pw[m] = lo | (hi << 16);
        }
        ((uint4*)pfx)[t] = make_uint4(pw[0], pw[1], pw[2], pw[3]);
    }
    __syncthreads();
    unsigned ub = ubS;
    // coords: bitmap walk -> sequential sorted float4 stores
    unsigned wq[8] = { q0.x, q0.y, q0.z, q0.w, q1.x, q1.y, q1.z, q1.w };
    unsigned rr = ub + excl;
    #pragma unroll
    for (int m = 0; m < 8; ++m) {
        unsigned w = wq[m];
        unsigned hi = ((unsigned)b << LOCAL_BITS) | ((unsigned)(8 * t + m) << 5);
        while (w) {
            unsigned bit = (unsigned)__ffs(w) - 1u;
            w &= w - 1u;
            unsigned key = hi | bit;
            out_coords[rr++] = make_float4((float)(key >> 21),
                                           (float)((key >> 14) & 127u),
                                           (float)((key >> 7) & 127u),
                                           (float)(key & 127u));
        }
    }
    // feats: waves 1..15 from cached pk (wave 0 owned no points)
    if (t >= 64) {
        #pragma unroll
        for (int k = 0; k < 5; ++k) {
            unsigned p = (unsigned)(t - 64) + (unsigned)k * 960u;
            if (p < tot) {
                unsigned v = pk[k];
                unsigned lk = v & LKMASK;
                unsigned wd = lk >> 5;
                unsigned lr = (unsigned)pfx[wd] + __popc(bm[wd] & ((1u << (lk & 31u)) - 1u));
                atomicAdd(&fe[lr], kl[v >> 29]);
            }
        }
    }
    __syncthreads();
    for (unsigned i = (unsigned)t; i < cnt; i += 1024u)
        out_feats[ub + i] = fe[i];
    // tail fill: rows [T, n)
    unsigned T = totS;
    for (unsigned r = T + (unsigned)(b * 1024 + t); r < (unsigned)n; r += N_BUCKETS * 1024u) {
        out_coords[r] = make_float4(-1.f, -1.f, -1.f, -1.f);
        out_feats[r] = 0.f;
    }
}

extern "C" void kernel_launch(void* const* d_in, const int* in_sizes, int n_in,
                              void* d_out, int out_size, void* d_ws, size_t ws_size,
                              hipStream_t stream) {
    const int4* coords = (const int4*)d_in[0];
    const float* kern  = (const float*)d_in[1];
    int N = in_sizes[0] / 4;

    float* out = (float*)d_out;                   // [4N floats coords][N floats feats]
    float4* out_coords = (float4*)out;
    float* out_feats = out + (size_t)4 * N;

    unsigned* gcur   = (unsigned*)d_ws;                          // 64 KB cursors [xcd][bucket]
    unsigned* ucount = gcur + (size_t)N_BUCKETS * NXCD;          // 8 KB (16B-aligned)
    unsigned* pairs  = ucount + (size_t)N_BUCKETS;               // 32 MB windows

    hipMemsetAsync(gcur, 0, (size_t)N_BUCKETS * NXCD * sizeof(unsigned), stream);

    int ntiles = (N + TILE - 1) / TILE;           // 489 for N=4M
    build_pass<<<ntiles, 1024, 0, stream>>>(coords, gcur, pairs, N);
    count_pass<<<N_BUCKETS, 512, 0, stream>>>(pairs, gcur, ucount);
    emit_pass<<<N_BUCKETS, 1024, 0, stream>>>(pairs, gcur, ucount, kern,
                                              out_coords, out_feats, N);
}